// Round 10
// baseline (502.306 us; speedup 1.0000x reference)
//
#include <hip/hip_runtime.h>
#include <hip/hip_fp8.h>

// StargazerGNN: 3-layer GCN + graph mean-pool + linear head.
// N=100000 nodes, E=1600000 edges, G=64 graphs, D=128.
// R9 post-mortem: agg_mm gather bound by random-granule fabric ceiling
// (~850 GB/s): FETCH 82MB / 96us. h-table (12.8MB) >> 4MB per-XCD L2.
// R10: dim-quartered aggregation — 4 phases, each gathers a 32B row-quarter;
// active set 3.2MB < 4MB L2 -> gathers become L2 hits after compulsory
// misses. 8 lanes/node (2 edge slots x 4 dim-lanes), shfl_xor slot reduce.

#define DHID 128
#define NGRAPH 64
#define NPASS 8
#define CAPSH 6  // 64 slots per node

typedef float floatx2 __attribute__((ext_vector_type(2)));

__device__ __forceinline__ unsigned int ftof8(float f) {
  __hip_fp8_e4m3 t(f);
  return (unsigned int)t.__x;
}

__device__ __forceinline__ void fma4(float4& a, float s, const float4& w) {
  a.x = fmaf(s, w.x, a.x);
  a.y = fmaf(s, w.y, a.y);
  a.z = fmaf(s, w.z, a.z);
  a.w = fmaf(s, w.w, a.w);
}

// Packed fp8 e4m3 decode: 8 dims in a uint2 -> 4 v_cvt_pk_f32_fp8 + 8 adds.
__device__ __forceinline__ void dec8(uint2 v, float* acc) {
  floatx2 f0 = __builtin_amdgcn_cvt_pk_f32_fp8((int)v.x, false);
  floatx2 f1 = __builtin_amdgcn_cvt_pk_f32_fp8((int)v.x, true);
  floatx2 f2 = __builtin_amdgcn_cvt_pk_f32_fp8((int)v.y, false);
  floatx2 f3 = __builtin_amdgcn_cvt_pk_f32_fp8((int)v.y, true);
  acc[0] += f0.x; acc[1] += f0.y;
  acc[2] += f1.x; acc[3] += f1.y;
  acc[4] += f2.x; acc[5] += f2.y;
  acc[6] += f3.x; acc[7] += f3.y;
}

// cur[n] = n*CAP (fixed-capacity CSR cursor init).
__global__ void k_init(int* __restrict__ cur, int N) {
  int n = blockIdx.x * 256 + threadIdx.x;
  if (n < N) cur[n] = n << CAPSH;
}

// Scatter pass: edges with dst in [lo,hi) claim a slot in their node's
// fixed-cap segment; degout counted exactly once per edge via (e&7)==pass.
__global__ void k_scatter(const int* __restrict__ src, const int* __restrict__ dst,
                          int* __restrict__ cur, int* __restrict__ eidx,
                          int* __restrict__ degout, int E, int lo, int hi, int pass) {
  int e = blockIdx.x * 256 + threadIdx.x;
  if (e >= E) return;
  int d = dst[e];
  int s = src[e];
  if ((e & (NPASS - 1)) == pass) atomicAdd(&degout[s], 1);
  if (d >= lo && d < hi) {
    int p = atomicAdd(&cur[d], 1);
    if (p < ((d + 1) << CAPSH)) eidx[p] = s;  // clamp (never hits: deg<<64)
  }
}

// degin from cursors; nodeval = degin*rsqrt(max(degout,1)); per-graph counts.
__global__ __launch_bounds__(256) void k_redeg(
    const int* __restrict__ cur, const int* __restrict__ degout,
    const int* __restrict__ gid, int* __restrict__ degin,
    float* __restrict__ nodeval, float* __restrict__ countsF, int N) {
  __shared__ float lcounts[NGRAPH];
  int tid = threadIdx.x;
  int n = blockIdx.x * 256 + tid;
  if (tid < NGRAPH) lcounts[tid] = 0.0f;
  __syncthreads();
  if (n < N) {
    int di = min(cur[n] - (n << CAPSH), 1 << CAPSH);
    degin[n] = di;
    nodeval[n] = (float)di * rsqrtf(fmaxf((float)degout[n], 1.0f));
    atomicAdd(&lcounts[gid[n]], 1.0f);
  }
  __syncthreads();
  if (tid < NGRAPH) {
    float c = lcounts[tid];
    if (c != 0.0f) atomicAdd(&countsF[tid], c);
  }
}

// ---- Layer 1 (rank-1) ----
__global__ void k_l1_agg(const float* __restrict__ nodeval, const int* __restrict__ degin,
                         const int* __restrict__ eidx, float* __restrict__ agg1, int N) {
  int n = blockIdx.x * 256 + threadIdx.x;
  if (n >= N) return;
  int o = n << CAPSH, c = degin[n];
  float acc = 0.0f;
  for (int i = 0; i < c; ++i) acc += nodeval[eidx[o + i]];
  agg1[n] = acc;
}

// hA[n][j] = relu(agg1[n]*nd*W1[j] + b1[j]) * ns, stored fp8 e4m3.
__global__ void k_l1_h(const int* __restrict__ degin, const int* __restrict__ degout,
                       const float* __restrict__ agg1, const float* __restrict__ W1,
                       const float* __restrict__ b1, unsigned char* __restrict__ hA,
                       int N) {
  int idx = blockIdx.x * 256 + threadIdx.x;  // N*16 groups of 8 dims
  int n = idx >> 4, c = idx & 15;
  if (n >= N) return;
  float nd = rsqrtf(fmaxf((float)degin[n], 1.0f));
  float ns = rsqrtf(fmaxf((float)degout[n], 1.0f));
  float x = agg1[n] * nd;
  unsigned int lo = 0, hi = 0;
#pragma unroll
  for (int j = 0; j < 4; ++j) {
    float v = fmaxf(fmaf(x, W1[c * 8 + j], b1[c * 8 + j]), 0.0f) * ns;
    lo |= ftof8(v) << (8 * j);
  }
#pragma unroll
  for (int j = 0; j < 4; ++j) {
    float v = fmaxf(fmaf(x, W1[c * 8 + 4 + j], b1[c * 8 + 4 + j]), 0.0f) * ns;
    hi |= ftof8(v) << (8 * j);
  }
  *(uint2*)(hA + (size_t)n * DHID + c * 8) = make_uint2(lo, hi);
}

// ---- Fused per-layer kernel: dim-quartered CSR aggregation into LDS
// (fp8 gather, packed decode; active gather set 3.2MB = L2-resident),
// then dense 128x128 matmul. MODE==1 fuses the graph mean-pool numerator. ----
template <int MODE>
__global__ __launch_bounds__(256) void k_agg_mm(
    const unsigned char* __restrict__ hs, const int* __restrict__ degin,
    const int* __restrict__ degout, const int* __restrict__ eidx,
    const float* __restrict__ W, const float* __restrict__ bias,
    unsigned char* __restrict__ hOut, const int* __restrict__ gid,
    float* __restrict__ hg, int N) {
  __shared__ float xl[32][DHID];
  const int tid = threadIdx.x;
  const int base = blockIdx.x * 32;

  // 8 lanes per node: 2 edge slots x 4 dim-lanes (8 dims each = 32B quarter).
  {
    const int n = tid >> 3;        // node 0..31
    const int sl = (tid >> 2) & 1; // edge slot (stride 2)
    const int l4 = tid & 3;        // dim-lane within quarter
    const int node = base + n;
    const int deg = (node < N) ? degin[node] : 0;
    const int o = node << CAPSH;
    const float nd = rsqrtf(fmaxf((float)deg, 1.0f));

#pragma unroll
    for (int q = 0; q < 4; ++q) {
      float acc[8] = {0.f, 0.f, 0.f, 0.f, 0.f, 0.f, 0.f, 0.f};
      const unsigned char* hq = hs + q * 32 + l4 * 8;
      int i = sl;
      for (; i + 2 < deg; i += 4) {
        int s0 = eidx[o + i];
        int s1 = eidx[o + i + 2];
        uint2 v0 = *(const uint2*)(hq + ((size_t)s0 << 7));
        uint2 v1 = *(const uint2*)(hq + ((size_t)s1 << 7));
        dec8(v0, acc);
        dec8(v1, acc);
      }
      for (; i < deg; i += 2) {
        int s0 = eidx[o + i];
        uint2 v0 = *(const uint2*)(hq + ((size_t)s0 << 7));
        dec8(v0, acc);
      }
      // combine the two edge slots (lane^4 is the same node, other slot)
#pragma unroll
      for (int j = 0; j < 8; ++j) acc[j] += __shfl_xor(acc[j], 4, 64);
      if (sl == 0) {
        *((float4*)&xl[n][q * 32 + l4 * 8]) =
            make_float4(acc[0] * nd, acc[1] * nd, acc[2] * nd, acc[3] * nd);
        *((float4*)&xl[n][q * 32 + l4 * 8 + 4]) =
            make_float4(acc[4] * nd, acc[5] * nd, acc[6] * nd, acc[7] * nd);
      }
    }
  }
  __syncthreads();

  // Dense mm: thread = (ng: 8 groups x 4 nodes, jg: 32 x 4 cols).
  const int jg = tid & 31;
  const int ng = tid >> 5;
  const float* wj = W + jg * 4;

  float4 acc[4];
#pragma unroll
  for (int i = 0; i < 4; ++i) acc[i] = make_float4(0.f, 0.f, 0.f, 0.f);

#pragma unroll 4
  for (int k = 0; k < DHID; k += 4) {
    float4 w0 = *(const float4*)(wj + (size_t)(k + 0) * DHID);
    float4 w1 = *(const float4*)(wj + (size_t)(k + 1) * DHID);
    float4 w2 = *(const float4*)(wj + (size_t)(k + 2) * DHID);
    float4 w3 = *(const float4*)(wj + (size_t)(k + 3) * DHID);
#pragma unroll
    for (int i = 0; i < 4; ++i) {
      float4 x = *(const float4*)&xl[ng * 4 + i][k];
      fma4(acc[i], x.x, w0);
      fma4(acc[i], x.y, w1);
      fma4(acc[i], x.z, w2);
      fma4(acc[i], x.w, w3);
    }
  }

  float4 bb = *(const float4*)(bias + jg * 4);

  if (MODE == 0) {
#pragma unroll
    for (int i = 0; i < 4; ++i) {
      int node = base + ng * 4 + i;
      if (node < N) {
        float ns = rsqrtf(fmaxf((float)degout[node], 1.0f));
        unsigned int w = 0;
        w |= ftof8(fmaxf(acc[i].x + bb.x, 0.0f) * ns);
        w |= ftof8(fmaxf(acc[i].y + bb.y, 0.0f) * ns) << 8;
        w |= ftof8(fmaxf(acc[i].z + bb.z, 0.0f) * ns) << 16;
        w |= ftof8(fmaxf(acc[i].w + bb.w, 0.0f) * ns) << 24;
        *(unsigned int*)(hOut + (size_t)node * DHID + jg * 4) = w;
      }
    }
  } else {
    // h3 (unscaled, fp32) back into LDS, then fused graph-mean-pool numerator.
    __syncthreads();
#pragma unroll
    for (int i = 0; i < 4; ++i) {
      int n = ng * 4 + i;
      float4 r;
      r.x = fmaxf(acc[i].x + bb.x, 0.0f);
      r.y = fmaxf(acc[i].y + bb.y, 0.0f);
      r.z = fmaxf(acc[i].z + bb.z, 0.0f);
      r.w = fmaxf(acc[i].w + bb.w, 0.0f);
      *((float4*)&xl[n][0] + jg) = r;
    }
    __syncthreads();
    if (tid < DHID) {
      float s = 0.0f;
      int gcur = gid[base];
      for (int n = 0; n < 32; ++n) {
        int node = base + n;
        if (node >= N) break;
        int g = gid[node];
        if (g != gcur) {
          atomicAdd(&hg[gcur * DHID + tid], s);
          s = 0.0f;
          gcur = g;
        }
        s += xl[n][tid];
      }
      atomicAdd(&hg[gcur * DHID + tid], s);
    }
  }
}

// Final head: out[g][c] = (hg[g][:] @ Wc[:,c]) / clip(counts[g],1) + bc[c].
__global__ void k_out(const float* __restrict__ hg, const float* __restrict__ countsF,
                      const float* __restrict__ Wc, const float* __restrict__ bc,
                      float* __restrict__ out) {
  int t = threadIdx.x;  // 128 = 64 graphs x 2 outputs
  int g = t >> 1, c = t & 1;
  float acc = 0.0f;
  for (int d = 0; d < DHID; ++d) acc = fmaf(hg[g * DHID + d], Wc[d * 2 + c], acc);
  out[t] = acc / fmaxf(countsF[g], 1.0f) + bc[c];
}

extern "C" void kernel_launch(void* const* d_in, const int* in_sizes, int n_in,
                              void* d_out, int out_size, void* d_ws, size_t ws_size,
                              hipStream_t stream) {
  const int* src = (const int*)d_in[0];
  const int* dst = (const int*)d_in[1];
  const int* gid = (const int*)d_in[2];
  const float* W1 = (const float*)d_in[3];
  const float* b1 = (const float*)d_in[4];
  const float* W2 = (const float*)d_in[5];
  const float* b2 = (const float*)d_in[6];
  const float* W3 = (const float*)d_in[7];
  const float* b3 = (const float*)d_in[8];
  const float* Wc = (const float*)d_in[9];
  const float* bc = (const float*)d_in[10];
  float* out = (float*)d_out;
  const int E = in_sizes[0];
  const int N = in_sizes[2];
  const int NBLK = (N + 255) / 256;

  char* ws = (char*)d_ws;
  size_t o = 0;
  auto alloc = [&](size_t bytes) {
    void* p = ws + o;
    o += (bytes + 255) & ~(size_t)255;
    return p;
  };
  unsigned char* hA = (unsigned char*)alloc((size_t)N * DHID);
  unsigned char* hB = (unsigned char*)alloc((size_t)N * DHID);
  int* eidx = (int*)alloc(((size_t)N << CAPSH) * 4);  // fixed-cap CSR, 25.6MB
  size_t z0 = o;  // zero-init region
  int* degout = (int*)alloc((size_t)N * 4);
  float* hg = (float*)alloc((size_t)NGRAPH * DHID * 4);
  float* countsF = (float*)alloc((size_t)NGRAPH * 4);
  size_t z1 = o;  // end zero-init
  int* degin = (int*)alloc((size_t)N * 4);
  float* nodeval = (float*)alloc((size_t)N * 4);
  float* agg1 = (float*)alloc((size_t)N * 4);
  int* cur = (int*)alloc((size_t)N * 4);
  (void)ws_size;  // ~55 MB used

  hipMemsetAsync(ws + z0, 0, z1 - z0, stream);

  // Fixed-cap CSR build: no degree pre-count, no scan.
  k_init<<<NBLK, 256, 0, stream>>>(cur, N);
  const int span = (N + NPASS - 1) / NPASS;
  for (int p = 0; p < NPASS; ++p) {
    k_scatter<<<(E + 255) / 256, 256, 0, stream>>>(src, dst, cur, eidx, degout,
                                                   E, p * span, (p + 1) * span, p);
  }
  k_redeg<<<NBLK, 256, 0, stream>>>(cur, degout, gid, degin, nodeval, countsF, N);
  // Layer 1
  k_l1_agg<<<NBLK, 256, 0, stream>>>(nodeval, degin, eidx, agg1, N);
  k_l1_h<<<((size_t)N * 16 + 255) / 256, 256, 0, stream>>>(degin, degout, agg1, W1, b1, hA, N);
  // Layer 2 (fused agg+mm)
  k_agg_mm<0><<<(N + 31) / 32, 256, 0, stream>>>(hA, degin, degout, eidx, W2, b2, hB, gid, hg, N);
  // Layer 3 (+ fused mean-pool numerator)
  k_agg_mm<1><<<(N + 31) / 32, 256, 0, stream>>>(hB, degin, degout, eidx, W3, b3, nullptr, gid, hg, N);
  // Head
  k_out<<<1, 128, 0, stream>>>(hg, countsF, Wc, bc, out);
}

// Round 11
// 363.544 us; speedup vs baseline: 1.3817x; 1.3817x over previous
//
#include <hip/hip_runtime.h>
#include <hip/hip_fp8.h>

// StargazerGNN: 3-layer GCN + graph mean-pool + linear head.
// N=100000 nodes, E=1600000 edges, G=64 graphs, D=128.
// R10 post-mortem: dim-quartering FAILED (FETCH 82->319MB): fetch granularity
// is the 128B line, so quarter-reads refetch the same lines 4x. Reverted.
// Also learned: fabric can stream 2.1TB/s; R9 agg_mm (854GB/s) is request-
// rate/latency bound, near the ~26Gops/s random-transaction ceiling.
// R11: degout via LDS-privatized block-partial histograms (NO global atomics,
// deterministic int sums) -> atomic ops 3.2M -> 1.6M (cur only).

#define DHID 128
#define NGRAPH 64
#define NPASS 8
#define CAPSH 6   // 64 slots per node (fixed-cap CSR)
#define HQ 7      // src-range passes for histogram
#define HR 16000  // range width (64KB LDS bins)
#define HB 64     // blocks per range

typedef float floatx2 __attribute__((ext_vector_type(2)));

__device__ __forceinline__ unsigned int ftof8(float f) {
  __hip_fp8_e4m3 t(f);
  return (unsigned int)t.__x;
}

__device__ __forceinline__ void fma4(float4& a, float s, const float4& w) {
  a.x = fmaf(s, w.x, a.x);
  a.y = fmaf(s, w.y, a.y);
  a.z = fmaf(s, w.z, a.z);
  a.w = fmaf(s, w.w, a.w);
}

// Packed fp8 e4m3 decode: 8 dims in a uint2 -> 4 v_cvt_pk_f32_fp8 + 8 adds.
__device__ __forceinline__ void dec8(uint2 v, float* acc) {
  floatx2 f0 = __builtin_amdgcn_cvt_pk_f32_fp8((int)v.x, false);
  floatx2 f1 = __builtin_amdgcn_cvt_pk_f32_fp8((int)v.x, true);
  floatx2 f2 = __builtin_amdgcn_cvt_pk_f32_fp8((int)v.y, false);
  floatx2 f3 = __builtin_amdgcn_cvt_pk_f32_fp8((int)v.y, true);
  acc[0] += f0.x; acc[1] += f0.y;
  acc[2] += f1.x; acc[3] += f1.y;
  acc[4] += f2.x; acc[5] += f2.y;
  acc[6] += f3.x; acc[7] += f3.y;
}

// cur[n] = n*CAP (fixed-capacity CSR cursor init).
__global__ void k_init(int* __restrict__ cur, int N) {
  int n = blockIdx.x * 256 + threadIdx.x;
  if (n < N) cur[n] = n << CAPSH;
}

// degout histogram, block-partial (no global atomics): block (b,q) counts
// src in [q*HR,(q+1)*HR) over its edge chunk in LDS, stores partial[q][b][:].
__global__ __launch_bounds__(256) void k_hist(const int* __restrict__ src,
                                              int* __restrict__ partial, int E) {
  __shared__ int lh[HR];  // 64 KB
  const int b = blockIdx.x;
  const int q = blockIdx.y;
  const int lo = q * HR;
  const int tid = threadIdx.x;
  for (int i = tid; i < HR; i += 256) lh[i] = 0;
  __syncthreads();
  const int per = (E + HB - 1) / HB;
  const int e1 = min(b * per + per, E);
  for (int e = b * per + tid; e < e1; e += 256) {
    unsigned s = (unsigned)(src[e] - lo);
    if (s < HR) atomicAdd(&lh[s], 1);  // LDS atomic (fast, rare conflicts)
  }
  __syncthreads();
  int* gp = partial + ((size_t)(q * HB + b)) * HR;
  for (int i = tid; i < HR; i += 256) gp[i] = lh[i];
}

// Scatter pass: edges with dst in [lo,hi) claim a slot in their node's
// fixed-cap segment (eidx window 3.2MB = L2-resident).
__global__ void k_scatter(const int* __restrict__ src, const int* __restrict__ dst,
                          int* __restrict__ cur, int* __restrict__ eidx,
                          int E, int lo, int hi) {
  int e = blockIdx.x * 256 + threadIdx.x;
  if (e >= E) return;
  int d = dst[e];
  if (d >= lo && d < hi) {
    int p = atomicAdd(&cur[d], 1);
    if (p < ((d + 1) << CAPSH)) eidx[p] = src[e];  // clamp (never hits)
  }
}

// degin from cursors; degout from partial sums (deterministic);
// nodeval = degin*rsqrt(max(degout,1)); per-graph node counts.
__global__ __launch_bounds__(256) void k_redeg(
    const int* __restrict__ cur, const int* __restrict__ partial,
    const int* __restrict__ gid, int* __restrict__ degin, int* __restrict__ degout,
    float* __restrict__ nodeval, float* __restrict__ countsF, int N) {
  __shared__ float lcounts[NGRAPH];
  int tid = threadIdx.x;
  int n = blockIdx.x * 256 + tid;
  if (tid < NGRAPH) lcounts[tid] = 0.0f;
  __syncthreads();
  if (n < N) {
    int q = n / HR;
    int r = n - q * HR;
    const int* gp = partial + ((size_t)q * HB) * HR + r;
    int dout = 0;
#pragma unroll
    for (int b = 0; b < HB; ++b) dout += gp[(size_t)b * HR];
    int di = min(cur[n] - (n << CAPSH), 1 << CAPSH);
    degin[n] = di;
    degout[n] = dout;
    nodeval[n] = (float)di * rsqrtf(fmaxf((float)dout, 1.0f));
    atomicAdd(&lcounts[gid[n]], 1.0f);
  }
  __syncthreads();
  if (tid < NGRAPH) {
    float c = lcounts[tid];
    if (c != 0.0f) atomicAdd(&countsF[tid], c);
  }
}

// ---- Layer 1 (rank-1) ----
__global__ void k_l1_agg(const float* __restrict__ nodeval, const int* __restrict__ degin,
                         const int* __restrict__ eidx, float* __restrict__ agg1, int N) {
  int n = blockIdx.x * 256 + threadIdx.x;
  if (n >= N) return;
  int o = n << CAPSH, c = degin[n];
  float acc = 0.0f;
  for (int i = 0; i < c; ++i) acc += nodeval[eidx[o + i]];
  agg1[n] = acc;
}

// hA[n][j] = relu(agg1[n]*nd*W1[j] + b1[j]) * ns, stored fp8 e4m3.
__global__ void k_l1_h(const int* __restrict__ degin, const int* __restrict__ degout,
                       const float* __restrict__ agg1, const float* __restrict__ W1,
                       const float* __restrict__ b1, unsigned char* __restrict__ hA,
                       int N) {
  int idx = blockIdx.x * 256 + threadIdx.x;  // N*16 groups of 8 dims
  int n = idx >> 4, c = idx & 15;
  if (n >= N) return;
  float nd = rsqrtf(fmaxf((float)degin[n], 1.0f));
  float ns = rsqrtf(fmaxf((float)degout[n], 1.0f));
  float x = agg1[n] * nd;
  unsigned int lo = 0, hi = 0;
#pragma unroll
  for (int j = 0; j < 4; ++j) {
    float v = fmaxf(fmaf(x, W1[c * 8 + j], b1[c * 8 + j]), 0.0f) * ns;
    lo |= ftof8(v) << (8 * j);
  }
#pragma unroll
  for (int j = 0; j < 4; ++j) {
    float v = fmaxf(fmaf(x, W1[c * 8 + 4 + j], b1[c * 8 + 4 + j]), 0.0f) * ns;
    hi |= ftof8(v) << (8 * j);
  }
  *(uint2*)(hA + (size_t)n * DHID + c * 8) = make_uint2(lo, hi);
}

// ---- Fused per-layer kernel (R9 structure): CSR-aggregate 32 nodes into LDS
// (fp8 gather, packed decode, 4-way edge ILP), then dense 128x128 matmul.
// MODE==1 fuses the graph mean-pool numerator. ----
template <int MODE>
__global__ __launch_bounds__(256) void k_agg_mm(
    const unsigned char* __restrict__ hs, const int* __restrict__ degin,
    const int* __restrict__ degout, const int* __restrict__ eidx,
    const float* __restrict__ W, const float* __restrict__ bias,
    unsigned char* __restrict__ hOut, const int* __restrict__ gid,
    float* __restrict__ hg, int N) {
  __shared__ float xl[32][DHID];
  const int tid = threadIdx.x;
  const int base = blockIdx.x * 32;
  const int g16 = tid >> 4;  // 16 groups of 16 lanes
  const int l16 = tid & 15;

  // Aggregate: each 16-lane group does 2 nodes; lane covers 8 dims (8B uint2).
  // 4 edges in flight per group to hide gather latency.
#pragma unroll
  for (int rep = 0; rep < 2; ++rep) {
    int n = g16 + rep * 16;
    int node = base + n;
    float acc[8] = {0.f, 0.f, 0.f, 0.f, 0.f, 0.f, 0.f, 0.f};
    if (node < N) {
      int o = node << CAPSH, c = degin[node];
      const unsigned char* hp = hs + l16 * 8;
      int i = 0;
      for (; i + 3 < c; i += 4) {
        int s0 = eidx[o + i + 0];
        int s1 = eidx[o + i + 1];
        int s2 = eidx[o + i + 2];
        int s3 = eidx[o + i + 3];
        uint2 v0 = *(const uint2*)(hp + ((size_t)s0 << 7));
        uint2 v1 = *(const uint2*)(hp + ((size_t)s1 << 7));
        uint2 v2 = *(const uint2*)(hp + ((size_t)s2 << 7));
        uint2 v3 = *(const uint2*)(hp + ((size_t)s3 << 7));
        dec8(v0, acc);
        dec8(v1, acc);
        dec8(v2, acc);
        dec8(v3, acc);
      }
      for (; i < c; ++i) {
        int s = eidx[o + i];
        uint2 v = *(const uint2*)(hp + ((size_t)s << 7));
        dec8(v, acc);
      }
      float nd = rsqrtf(fmaxf((float)c, 1.0f));
#pragma unroll
      for (int j = 0; j < 8; ++j) acc[j] *= nd;
    }
    *((float4*)&xl[n][l16 * 8]) = make_float4(acc[0], acc[1], acc[2], acc[3]);
    *((float4*)&xl[n][l16 * 8 + 4]) = make_float4(acc[4], acc[5], acc[6], acc[7]);
  }
  __syncthreads();

  // Dense mm: thread = (ng: 8 groups x 4 nodes, jg: 32 x 4 cols).
  const int jg = tid & 31;
  const int ng = tid >> 5;
  const float* wj = W + jg * 4;

  float4 acc[4];
#pragma unroll
  for (int i = 0; i < 4; ++i) acc[i] = make_float4(0.f, 0.f, 0.f, 0.f);

#pragma unroll 4
  for (int k = 0; k < DHID; k += 4) {
    float4 w0 = *(const float4*)(wj + (size_t)(k + 0) * DHID);
    float4 w1 = *(const float4*)(wj + (size_t)(k + 1) * DHID);
    float4 w2 = *(const float4*)(wj + (size_t)(k + 2) * DHID);
    float4 w3 = *(const float4*)(wj + (size_t)(k + 3) * DHID);
#pragma unroll
    for (int i = 0; i < 4; ++i) {
      float4 x = *(const float4*)&xl[ng * 4 + i][k];
      fma4(acc[i], x.x, w0);
      fma4(acc[i], x.y, w1);
      fma4(acc[i], x.z, w2);
      fma4(acc[i], x.w, w3);
    }
  }

  float4 bb = *(const float4*)(bias + jg * 4);

  if (MODE == 0) {
#pragma unroll
    for (int i = 0; i < 4; ++i) {
      int node = base + ng * 4 + i;
      if (node < N) {
        float ns = rsqrtf(fmaxf((float)degout[node], 1.0f));
        unsigned int w = 0;
        w |= ftof8(fmaxf(acc[i].x + bb.x, 0.0f) * ns);
        w |= ftof8(fmaxf(acc[i].y + bb.y, 0.0f) * ns) << 8;
        w |= ftof8(fmaxf(acc[i].z + bb.z, 0.0f) * ns) << 16;
        w |= ftof8(fmaxf(acc[i].w + bb.w, 0.0f) * ns) << 24;
        *(unsigned int*)(hOut + (size_t)node * DHID + jg * 4) = w;
      }
    }
  } else {
    // h3 (unscaled, fp32) back into LDS, then fused graph-mean-pool numerator.
    __syncthreads();
#pragma unroll
    for (int i = 0; i < 4; ++i) {
      int n = ng * 4 + i;
      float4 r;
      r.x = fmaxf(acc[i].x + bb.x, 0.0f);
      r.y = fmaxf(acc[i].y + bb.y, 0.0f);
      r.z = fmaxf(acc[i].z + bb.z, 0.0f);
      r.w = fmaxf(acc[i].w + bb.w, 0.0f);
      *((float4*)&xl[n][0] + jg) = r;
    }
    __syncthreads();
    if (tid < DHID) {
      float s = 0.0f;
      int gcur = gid[base];
      for (int n = 0; n < 32; ++n) {
        int node = base + n;
        if (node >= N) break;
        int g = gid[node];
        if (g != gcur) {
          atomicAdd(&hg[gcur * DHID + tid], s);
          s = 0.0f;
          gcur = g;
        }
        s += xl[n][tid];
      }
      atomicAdd(&hg[gcur * DHID + tid], s);
    }
  }
}

// Final head: out[g][c] = (hg[g][:] @ Wc[:,c]) / clip(counts[g],1) + bc[c].
__global__ void k_out(const float* __restrict__ hg, const float* __restrict__ countsF,
                      const float* __restrict__ Wc, const float* __restrict__ bc,
                      float* __restrict__ out) {
  int t = threadIdx.x;  // 128 = 64 graphs x 2 outputs
  int g = t >> 1, c = t & 1;
  float acc = 0.0f;
  for (int d = 0; d < DHID; ++d) acc = fmaf(hg[g * DHID + d], Wc[d * 2 + c], acc);
  out[t] = acc / fmaxf(countsF[g], 1.0f) + bc[c];
}

extern "C" void kernel_launch(void* const* d_in, const int* in_sizes, int n_in,
                              void* d_out, int out_size, void* d_ws, size_t ws_size,
                              hipStream_t stream) {
  const int* src = (const int*)d_in[0];
  const int* dst = (const int*)d_in[1];
  const int* gid = (const int*)d_in[2];
  const float* W1 = (const float*)d_in[3];
  const float* b1 = (const float*)d_in[4];
  const float* W2 = (const float*)d_in[5];
  const float* b2 = (const float*)d_in[6];
  const float* W3 = (const float*)d_in[7];
  const float* b3 = (const float*)d_in[8];
  const float* Wc = (const float*)d_in[9];
  const float* bc = (const float*)d_in[10];
  float* out = (float*)d_out;
  const int E = in_sizes[0];
  const int N = in_sizes[2];
  const int NBLK = (N + 255) / 256;

  char* ws = (char*)d_ws;
  size_t o = 0;
  auto alloc = [&](size_t bytes) {
    void* p = ws + o;
    o += (bytes + 255) & ~(size_t)255;
    return p;
  };
  unsigned char* hA = (unsigned char*)alloc((size_t)N * DHID);
  unsigned char* hB = (unsigned char*)alloc((size_t)N * DHID);
  int* eidx = (int*)alloc(((size_t)N << CAPSH) * 4);   // fixed-cap CSR, 25.6MB
  int* partial = (int*)alloc((size_t)HQ * HB * HR * 4);  // 28.7MB hist partials
  size_t z0 = o;  // zero-init region
  float* hg = (float*)alloc((size_t)NGRAPH * DHID * 4);
  float* countsF = (float*)alloc((size_t)NGRAPH * 4);
  size_t z1 = o;  // end zero-init
  int* degin = (int*)alloc((size_t)N * 4);
  int* degout = (int*)alloc((size_t)N * 4);
  float* nodeval = (float*)alloc((size_t)N * 4);
  float* agg1 = (float*)alloc((size_t)N * 4);
  int* cur = (int*)alloc((size_t)N * 4);
  (void)ws_size;  // ~84 MB used

  hipMemsetAsync(ws + z0, 0, z1 - z0, stream);

  // CSR build: fixed-cap (no degree pre-count/scan); degout via atomic-free
  // block-partial histograms; scatter = cur atomics only.
  k_init<<<NBLK, 256, 0, stream>>>(cur, N);
  k_hist<<<dim3(HB, HQ), 256, 0, stream>>>(src, partial, E);
  const int span = (N + NPASS - 1) / NPASS;
  for (int p = 0; p < NPASS; ++p) {
    k_scatter<<<(E + 255) / 256, 256, 0, stream>>>(src, dst, cur, eidx, E,
                                                   p * span, (p + 1) * span);
  }
  k_redeg<<<NBLK, 256, 0, stream>>>(cur, partial, gid, degin, degout, nodeval,
                                    countsF, N);
  // Layer 1
  k_l1_agg<<<NBLK, 256, 0, stream>>>(nodeval, degin, eidx, agg1, N);
  k_l1_h<<<((size_t)N * 16 + 255) / 256, 256, 0, stream>>>(degin, degout, agg1, W1, b1, hA, N);
  // Layer 2 (fused agg+mm)
  k_agg_mm<0><<<(N + 31) / 32, 256, 0, stream>>>(hA, degin, degout, eidx, W2, b2, hB, gid, hg, N);
  // Layer 3 (+ fused mean-pool numerator)
  k_agg_mm<1><<<(N + 31) / 32, 256, 0, stream>>>(hB, degin, degout, eidx, W3, b3, nullptr, gid, hg, N);
  // Head
  k_out<<<1, 128, 0, stream>>>(hg, countsF, Wc, bc, out);
}

// Round 12
// 361.565 us; speedup vs baseline: 1.3893x; 1.0055x over previous
//
#include <hip/hip_runtime.h>
#include <hip/hip_fp8.h>

// StargazerGNN: 3-layer GCN + graph mean-pool + linear head.
// N=100000 nodes, E=1600000 edges, G=64 graphs, D=128.
// R11 post-mortem: agg phase is LATENCY-bound, not ceiling-bound (R10 probe
// proved 16.4G misses/s sustainable; agg runs at 6.7G). Old layout: 16
// lanes/node -> only 4 distinct lines per wave-load instruction.
// R12: 8 lanes/node, uint4 full-row loads -> 8 distinct lines per wave-load;
// 8-way edge unroll via 2x int4 eidx prefetch -> ~4x MLP. All 32 nodes of a
// tile concurrent (no rep loop).

#define DHID 128
#define NGRAPH 64
#define NPASS 8
#define CAPSH 6   // 64 slots per node (fixed-cap CSR)
#define HQ 7      // src-range passes for histogram
#define HR 16000  // range width (64KB LDS bins)
#define HB 64     // blocks per range

typedef float floatx2 __attribute__((ext_vector_type(2)));

__device__ __forceinline__ unsigned int ftof8(float f) {
  __hip_fp8_e4m3 t(f);
  return (unsigned int)t.__x;
}

__device__ __forceinline__ void fma4(float4& a, float s, const float4& w) {
  a.x = fmaf(s, w.x, a.x);
  a.y = fmaf(s, w.y, a.y);
  a.z = fmaf(s, w.z, a.z);
  a.w = fmaf(s, w.w, a.w);
}

// Packed fp8 e4m3 decode: 16 dims in a uint4 -> 8 v_cvt_pk_f32_fp8 + 16 adds.
__device__ __forceinline__ void dec16(uint4 v, float* acc) {
  floatx2 f0 = __builtin_amdgcn_cvt_pk_f32_fp8((int)v.x, false);
  floatx2 f1 = __builtin_amdgcn_cvt_pk_f32_fp8((int)v.x, true);
  floatx2 f2 = __builtin_amdgcn_cvt_pk_f32_fp8((int)v.y, false);
  floatx2 f3 = __builtin_amdgcn_cvt_pk_f32_fp8((int)v.y, true);
  floatx2 f4 = __builtin_amdgcn_cvt_pk_f32_fp8((int)v.z, false);
  floatx2 f5 = __builtin_amdgcn_cvt_pk_f32_fp8((int)v.z, true);
  floatx2 f6 = __builtin_amdgcn_cvt_pk_f32_fp8((int)v.w, false);
  floatx2 f7 = __builtin_amdgcn_cvt_pk_f32_fp8((int)v.w, true);
  acc[0] += f0.x;  acc[1] += f0.y;  acc[2] += f1.x;  acc[3] += f1.y;
  acc[4] += f2.x;  acc[5] += f2.y;  acc[6] += f3.x;  acc[7] += f3.y;
  acc[8] += f4.x;  acc[9] += f4.y;  acc[10] += f5.x; acc[11] += f5.y;
  acc[12] += f6.x; acc[13] += f6.y; acc[14] += f7.x; acc[15] += f7.y;
}

// cur[n] = n*CAP (fixed-capacity CSR cursor init).
__global__ void k_init(int* __restrict__ cur, int N) {
  int n = blockIdx.x * 256 + threadIdx.x;
  if (n < N) cur[n] = n << CAPSH;
}

// degout histogram, block-partial (no global atomics): block (b,q) counts
// src in [q*HR,(q+1)*HR) over its edge chunk in LDS, stores partial[q][b][:].
__global__ __launch_bounds__(256) void k_hist(const int* __restrict__ src,
                                              int* __restrict__ partial, int E) {
  __shared__ int lh[HR];  // 64 KB
  const int b = blockIdx.x;
  const int q = blockIdx.y;
  const int lo = q * HR;
  const int tid = threadIdx.x;
  for (int i = tid; i < HR; i += 256) lh[i] = 0;
  __syncthreads();
  const int per = (E + HB - 1) / HB;
  const int e1 = min(b * per + per, E);
  for (int e = b * per + tid; e < e1; e += 256) {
    unsigned s = (unsigned)(src[e] - lo);
    if (s < HR) atomicAdd(&lh[s], 1);  // LDS atomic (fast, rare conflicts)
  }
  __syncthreads();
  int* gp = partial + ((size_t)(q * HB + b)) * HR;
  for (int i = tid; i < HR; i += 256) gp[i] = lh[i];
}

// Scatter pass: edges with dst in [lo,hi) claim a slot in their node's
// fixed-cap segment (eidx window 3.2MB = L2-resident).
__global__ void k_scatter(const int* __restrict__ src, const int* __restrict__ dst,
                          int* __restrict__ cur, int* __restrict__ eidx,
                          int E, int lo, int hi) {
  int e = blockIdx.x * 256 + threadIdx.x;
  if (e >= E) return;
  int d = dst[e];
  if (d >= lo && d < hi) {
    int p = atomicAdd(&cur[d], 1);
    if (p < ((d + 1) << CAPSH)) eidx[p] = src[e];  // clamp (never hits)
  }
}

// degin from cursors; degout from partial sums (deterministic);
// nodeval = degin*rsqrt(max(degout,1)); per-graph node counts.
__global__ __launch_bounds__(256) void k_redeg(
    const int* __restrict__ cur, const int* __restrict__ partial,
    const int* __restrict__ gid, int* __restrict__ degin, int* __restrict__ degout,
    float* __restrict__ nodeval, float* __restrict__ countsF, int N) {
  __shared__ float lcounts[NGRAPH];
  int tid = threadIdx.x;
  int n = blockIdx.x * 256 + tid;
  if (tid < NGRAPH) lcounts[tid] = 0.0f;
  __syncthreads();
  if (n < N) {
    int q = n / HR;
    int r = n - q * HR;
    const int* gp = partial + ((size_t)q * HB) * HR + r;
    int dout = 0;
#pragma unroll
    for (int b = 0; b < HB; ++b) dout += gp[(size_t)b * HR];
    int di = min(cur[n] - (n << CAPSH), 1 << CAPSH);
    degin[n] = di;
    degout[n] = dout;
    nodeval[n] = (float)di * rsqrtf(fmaxf((float)dout, 1.0f));
    atomicAdd(&lcounts[gid[n]], 1.0f);
  }
  __syncthreads();
  if (tid < NGRAPH) {
    float c = lcounts[tid];
    if (c != 0.0f) atomicAdd(&countsF[tid], c);
  }
}

// ---- Layer 1 (rank-1) ----
__global__ void k_l1_agg(const float* __restrict__ nodeval, const int* __restrict__ degin,
                         const int* __restrict__ eidx, float* __restrict__ agg1, int N) {
  int n = blockIdx.x * 256 + threadIdx.x;
  if (n >= N) return;
  int o = n << CAPSH, c = degin[n];
  float acc = 0.0f;
  for (int i = 0; i < c; ++i) acc += nodeval[eidx[o + i]];
  agg1[n] = acc;
}

// hA[n][j] = relu(agg1[n]*nd*W1[j] + b1[j]) * ns, stored fp8 e4m3.
__global__ void k_l1_h(const int* __restrict__ degin, const int* __restrict__ degout,
                       const float* __restrict__ agg1, const float* __restrict__ W1,
                       const float* __restrict__ b1, unsigned char* __restrict__ hA,
                       int N) {
  int idx = blockIdx.x * 256 + threadIdx.x;  // N*16 groups of 8 dims
  int n = idx >> 4, c = idx & 15;
  if (n >= N) return;
  float nd = rsqrtf(fmaxf((float)degin[n], 1.0f));
  float ns = rsqrtf(fmaxf((float)degout[n], 1.0f));
  float x = agg1[n] * nd;
  unsigned int lo = 0, hi = 0;
#pragma unroll
  for (int j = 0; j < 4; ++j) {
    float v = fmaxf(fmaf(x, W1[c * 8 + j], b1[c * 8 + j]), 0.0f) * ns;
    lo |= ftof8(v) << (8 * j);
  }
#pragma unroll
  for (int j = 0; j < 4; ++j) {
    float v = fmaxf(fmaf(x, W1[c * 8 + 4 + j], b1[c * 8 + 4 + j]), 0.0f) * ns;
    hi |= ftof8(v) << (8 * j);
  }
  *(uint2*)(hA + (size_t)n * DHID + c * 8) = make_uint2(lo, hi);
}

// ---- Fused per-layer kernel: CSR-aggregate 32 nodes into LDS (fp8 gather:
// 8 lanes/node, uint4 full-row loads = 8 distinct lines per wave-load, 8-way
// edge unroll), then dense 128x128 matmul. MODE==1 fuses graph mean-pool. ----
template <int MODE>
__global__ __launch_bounds__(256) void k_agg_mm(
    const unsigned char* __restrict__ hs, const int* __restrict__ degin,
    const int* __restrict__ degout, const int* __restrict__ eidx,
    const float* __restrict__ W, const float* __restrict__ bias,
    unsigned char* __restrict__ hOut, const int* __restrict__ gid,
    float* __restrict__ hg, int N) {
  __shared__ float xl[32][DHID];
  const int tid = threadIdx.x;
  const int base = blockIdx.x * 32;

  // Aggregate: 8 lanes per node (lane covers 16 dims = 16B uint4); all 32
  // nodes concurrent; 8 edges in flight per group.
  {
    const int n = tid >> 3;   // node slot 0..31
    const int l8 = tid & 7;   // dim-lane
    const int node = base + n;
    const int deg = (node < N) ? degin[node] : 0;
    const int o = node << CAPSH;
    const unsigned char* hp = hs + l8 * 16;
    float acc[16];
#pragma unroll
    for (int j = 0; j < 16; ++j) acc[j] = 0.0f;

    int i = 0;
    for (; i + 7 < deg; i += 8) {
      int4 ea = *(const int4*)(eidx + o + i);
      int4 eb = *(const int4*)(eidx + o + i + 4);
      uint4 v0 = *(const uint4*)(hp + ((size_t)ea.x << 7));
      uint4 v1 = *(const uint4*)(hp + ((size_t)ea.y << 7));
      uint4 v2 = *(const uint4*)(hp + ((size_t)ea.z << 7));
      uint4 v3 = *(const uint4*)(hp + ((size_t)ea.w << 7));
      uint4 v4 = *(const uint4*)(hp + ((size_t)eb.x << 7));
      uint4 v5 = *(const uint4*)(hp + ((size_t)eb.y << 7));
      uint4 v6 = *(const uint4*)(hp + ((size_t)eb.z << 7));
      uint4 v7 = *(const uint4*)(hp + ((size_t)eb.w << 7));
      dec16(v0, acc); dec16(v1, acc); dec16(v2, acc); dec16(v3, acc);
      dec16(v4, acc); dec16(v5, acc); dec16(v6, acc); dec16(v7, acc);
    }
    for (; i + 3 < deg; i += 4) {
      int4 ea = *(const int4*)(eidx + o + i);
      uint4 v0 = *(const uint4*)(hp + ((size_t)ea.x << 7));
      uint4 v1 = *(const uint4*)(hp + ((size_t)ea.y << 7));
      uint4 v2 = *(const uint4*)(hp + ((size_t)ea.z << 7));
      uint4 v3 = *(const uint4*)(hp + ((size_t)ea.w << 7));
      dec16(v0, acc); dec16(v1, acc); dec16(v2, acc); dec16(v3, acc);
    }
    for (; i < deg; ++i) {
      uint4 v = *(const uint4*)(hp + ((size_t)eidx[o + i] << 7));
      dec16(v, acc);
    }
    const float nd = rsqrtf(fmaxf((float)deg, 1.0f));
#pragma unroll
    for (int j = 0; j < 16; ++j) acc[j] *= nd;
#pragma unroll
    for (int j = 0; j < 4; ++j)
      *((float4*)&xl[n][l8 * 16 + j * 4]) =
          make_float4(acc[j * 4], acc[j * 4 + 1], acc[j * 4 + 2], acc[j * 4 + 3]);
  }
  __syncthreads();

  // Dense mm: thread = (ng: 8 groups x 4 nodes, jg: 32 x 4 cols).
  const int jg = tid & 31;
  const int ng = tid >> 5;
  const float* wj = W + jg * 4;

  float4 acc[4];
#pragma unroll
  for (int i = 0; i < 4; ++i) acc[i] = make_float4(0.f, 0.f, 0.f, 0.f);

#pragma unroll 4
  for (int k = 0; k < DHID; k += 4) {
    float4 w0 = *(const float4*)(wj + (size_t)(k + 0) * DHID);
    float4 w1 = *(const float4*)(wj + (size_t)(k + 1) * DHID);
    float4 w2 = *(const float4*)(wj + (size_t)(k + 2) * DHID);
    float4 w3 = *(const float4*)(wj + (size_t)(k + 3) * DHID);
#pragma unroll
    for (int i = 0; i < 4; ++i) {
      float4 x = *(const float4*)&xl[ng * 4 + i][k];
      fma4(acc[i], x.x, w0);
      fma4(acc[i], x.y, w1);
      fma4(acc[i], x.z, w2);
      fma4(acc[i], x.w, w3);
    }
  }

  float4 bb = *(const float4*)(bias + jg * 4);

  if (MODE == 0) {
#pragma unroll
    for (int i = 0; i < 4; ++i) {
      int node = base + ng * 4 + i;
      if (node < N) {
        float ns = rsqrtf(fmaxf((float)degout[node], 1.0f));
        unsigned int w = 0;
        w |= ftof8(fmaxf(acc[i].x + bb.x, 0.0f) * ns);
        w |= ftof8(fmaxf(acc[i].y + bb.y, 0.0f) * ns) << 8;
        w |= ftof8(fmaxf(acc[i].z + bb.z, 0.0f) * ns) << 16;
        w |= ftof8(fmaxf(acc[i].w + bb.w, 0.0f) * ns) << 24;
        *(unsigned int*)(hOut + (size_t)node * DHID + jg * 4) = w;
      }
    }
  } else {
    // h3 (unscaled, fp32) back into LDS, then fused graph-mean-pool numerator.
    __syncthreads();
#pragma unroll
    for (int i = 0; i < 4; ++i) {
      int n = ng * 4 + i;
      float4 r;
      r.x = fmaxf(acc[i].x + bb.x, 0.0f);
      r.y = fmaxf(acc[i].y + bb.y, 0.0f);
      r.z = fmaxf(acc[i].z + bb.z, 0.0f);
      r.w = fmaxf(acc[i].w + bb.w, 0.0f);
      *((float4*)&xl[n][0] + jg) = r;
    }
    __syncthreads();
    if (tid < DHID) {
      float s = 0.0f;
      int gcur = gid[base];
      for (int n = 0; n < 32; ++n) {
        int node = base + n;
        if (node >= N) break;
        int g = gid[node];
        if (g != gcur) {
          atomicAdd(&hg[gcur * DHID + tid], s);
          s = 0.0f;
          gcur = g;
        }
        s += xl[n][tid];
      }
      atomicAdd(&hg[gcur * DHID + tid], s);
    }
  }
}

// Final head: out[g][c] = (hg[g][:] @ Wc[:,c]) / clip(counts[g],1) + bc[c].
__global__ void k_out(const float* __restrict__ hg, const float* __restrict__ countsF,
                      const float* __restrict__ Wc, const float* __restrict__ bc,
                      float* __restrict__ out) {
  int t = threadIdx.x;  // 128 = 64 graphs x 2 outputs
  int g = t >> 1, c = t & 1;
  float acc = 0.0f;
  for (int d = 0; d < DHID; ++d) acc = fmaf(hg[g * DHID + d], Wc[d * 2 + c], acc);
  out[t] = acc / fmaxf(countsF[g], 1.0f) + bc[c];
}

extern "C" void kernel_launch(void* const* d_in, const int* in_sizes, int n_in,
                              void* d_out, int out_size, void* d_ws, size_t ws_size,
                              hipStream_t stream) {
  const int* src = (const int*)d_in[0];
  const int* dst = (const int*)d_in[1];
  const int* gid = (const int*)d_in[2];
  const float* W1 = (const float*)d_in[3];
  const float* b1 = (const float*)d_in[4];
  const float* W2 = (const float*)d_in[5];
  const float* b2 = (const float*)d_in[6];
  const float* W3 = (const float*)d_in[7];
  const float* b3 = (const float*)d_in[8];
  const float* Wc = (const float*)d_in[9];
  const float* bc = (const float*)d_in[10];
  float* out = (float*)d_out;
  const int E = in_sizes[0];
  const int N = in_sizes[2];
  const int NBLK = (N + 255) / 256;

  char* ws = (char*)d_ws;
  size_t o = 0;
  auto alloc = [&](size_t bytes) {
    void* p = ws + o;
    o += (bytes + 255) & ~(size_t)255;
    return p;
  };
  unsigned char* hA = (unsigned char*)alloc((size_t)N * DHID);
  unsigned char* hB = (unsigned char*)alloc((size_t)N * DHID);
  int* eidx = (int*)alloc(((size_t)N << CAPSH) * 4);   // fixed-cap CSR, 25.6MB
  int* partial = (int*)alloc((size_t)HQ * HB * HR * 4);  // 28.7MB hist partials
  size_t z0 = o;  // zero-init region
  float* hg = (float*)alloc((size_t)NGRAPH * DHID * 4);
  float* countsF = (float*)alloc((size_t)NGRAPH * 4);
  size_t z1 = o;  // end zero-init
  int* degin = (int*)alloc((size_t)N * 4);
  int* degout = (int*)alloc((size_t)N * 4);
  float* nodeval = (float*)alloc((size_t)N * 4);
  float* agg1 = (float*)alloc((size_t)N * 4);
  int* cur = (int*)alloc((size_t)N * 4);
  (void)ws_size;  // ~84 MB used

  hipMemsetAsync(ws + z0, 0, z1 - z0, stream);

  // CSR build: fixed-cap (no degree pre-count/scan); degout via atomic-free
  // block-partial histograms; scatter = cur atomics only.
  k_init<<<NBLK, 256, 0, stream>>>(cur, N);
  k_hist<<<dim3(HB, HQ), 256, 0, stream>>>(src, partial, E);
  const int span = (N + NPASS - 1) / NPASS;
  for (int p = 0; p < NPASS; ++p) {
    k_scatter<<<(E + 255) / 256, 256, 0, stream>>>(src, dst, cur, eidx, E,
                                                   p * span, (p + 1) * span);
  }
  k_redeg<<<NBLK, 256, 0, stream>>>(cur, partial, gid, degin, degout, nodeval,
                                    countsF, N);
  // Layer 1
  k_l1_agg<<<NBLK, 256, 0, stream>>>(nodeval, degin, eidx, agg1, N);
  k_l1_h<<<((size_t)N * 16 + 255) / 256, 256, 0, stream>>>(degin, degout, agg1, W1, b1, hA, N);
  // Layer 2 (fused agg+mm)
  k_agg_mm<0><<<(N + 31) / 32, 256, 0, stream>>>(hA, degin, degout, eidx, W2, b2, hB, gid, hg, N);
  // Layer 3 (+ fused mean-pool numerator)
  k_agg_mm<1><<<(N + 31) / 32, 256, 0, stream>>>(hB, degin, degout, eidx, W3, b3, nullptr, gid, hg, N);
  // Head
  k_out<<<1, 128, 0, stream>>>(hg, countsF, Wc, bc, out);
}